// Round 1
// baseline (419.564 us; speedup 1.0000x reference)
//
#include <hip/hip_runtime.h>

// ---------------------------------------------------------------------------
// Arcface-like: xn = x/||x||_F ; scores[b,p,w,v] = 5 * dot(xn[b,i,w,:], xn[b,j,v,:])
//   for (i,j) = triu_indices(16, k=1)[p], plus first-match "argmax" targets.
// B=32, S=16, W=128, h=256, P=120.
// Strategy: compute raw fp32 dots via bf16 MFMA (16x16x32), scale by s/norm2.
// ---------------------------------------------------------------------------

typedef __attribute__((ext_vector_type(8))) short short8;   // 8 bf16 in 4 VGPRs
typedef __attribute__((ext_vector_type(4))) float floatx4;  // MFMA accumulator

#define BDIM 256
#define LDA 72          // 64 + 8 pad (bf16 elems); row stride = 144 B (16B-aligned)

static __device__ __forceinline__ unsigned short f2bf(float f) {
    // round-to-nearest-even fp32 -> bf16 (inputs are finite normals)
    unsigned int u = __builtin_bit_cast(unsigned int, f);
    u += 0x7FFFu + ((u >> 16) & 1u);
    return (unsigned short)(u >> 16);
}

// ---------------- Kernel 1: sum of squares of x (16.7M floats) --------------
__global__ void sumsq_kernel(const float* __restrict__ x,
                             float* __restrict__ out, int n4) {
    const float4* x4 = reinterpret_cast<const float4*>(x);
    int tid = blockIdx.x * blockDim.x + threadIdx.x;
    int stride = gridDim.x * blockDim.x;
    float s = 0.f;
    for (int idx = tid; idx < n4; idx += stride) {
        float4 v = x4[idx];
        s += v.x * v.x + v.y * v.y + v.z * v.z + v.w * v.w;
    }
    // wave64 reduce
    #pragma unroll
    for (int off = 32; off > 0; off >>= 1) s += __shfl_down(s, off, 64);
    __shared__ float ws[4];
    int lane = threadIdx.x & 63, wv = threadIdx.x >> 6;
    if (lane == 0) ws[wv] = s;
    __syncthreads();
    if (threadIdx.x == 0) {
        atomicAdd(out, ws[0] + ws[1] + ws[2] + ws[3]);
    }
}

// ---------------- Kernel 2: per-(b,p) 128x128x256 NT-GEMM + targets ---------
__global__ __launch_bounds__(BDIM, 2) void pair_gemm_kernel(
    const float* __restrict__ x, const int* __restrict__ target,
    const float* __restrict__ norm2p, float* __restrict__ out_scores,
    float* __restrict__ out_tgt)
{
    __shared__ __align__(16) unsigned short lds_a[128 * LDA];
    __shared__ __align__(16) unsigned short lds_b[128 * LDA];
    __shared__ int tj_s[128];

    const int bp = blockIdx.x;        // 0..3839
    const int b  = bp / 120;
    const int p  = bp - b * 120;
    // decode p -> (i, j) per np.triu_indices(16, k=1) row-major order
    int i = 0, rem = p;
    while (rem >= 15 - i) { rem -= 15 - i; ++i; }
    const int j = i + 1 + rem;

    const float* Ag = x + (size_t)(b * 16 + i) * (128 * 256);
    const float* Bg = x + (size_t)(b * 16 + j) * (128 * 256);

    const int tid  = threadIdx.x;
    const int lane = tid & 63;
    const int wave = tid >> 6;
    const int wm   = (wave >> 1) * 64;   // wave row (m) offset in 128x128 tile
    const int wn   = (wave & 1)  * 64;   // wave col (n) offset
    const int r    = lane & 15;
    const int q    = lane >> 4;

    // fused target pass (uses tj_s; no dependency on lds_a/b yet)
    if (tid < 128) tj_s[tid] = target[(size_t)(b * 16 + j) * 128 + tid];

    floatx4 acc[4][4] = {};

    for (int k0 = 0; k0 < 256; k0 += 64) {
        // ---- stage A & B 128x64 fp32 tiles -> bf16 LDS ----
        #pragma unroll
        for (int it = 0; it < 8; ++it) {
            int f   = it * BDIM + tid;     // float4 index 0..2047
            int row = f >> 4;              // 0..127
            int c4  = (f & 15) * 4;        // 0..60
            float4 av = *reinterpret_cast<const float4*>(Ag + (size_t)row * 256 + k0 + c4);
            float4 bv = *reinterpret_cast<const float4*>(Bg + (size_t)row * 256 + k0 + c4);
            uint2 pa, pb;
            pa.x = (unsigned)f2bf(av.x) | ((unsigned)f2bf(av.y) << 16);
            pa.y = (unsigned)f2bf(av.z) | ((unsigned)f2bf(av.w) << 16);
            pb.x = (unsigned)f2bf(bv.x) | ((unsigned)f2bf(bv.y) << 16);
            pb.y = (unsigned)f2bf(bv.z) | ((unsigned)f2bf(bv.w) << 16);
            *reinterpret_cast<uint2*>(&lds_a[row * LDA + c4]) = pa;
            *reinterpret_cast<uint2*>(&lds_b[row * LDA + c4]) = pb;
        }
        __syncthreads();

        // ---- 2 MFMA K-steps of 32 within this BK=64 slab ----
        #pragma unroll
        for (int ks = 0; ks < 2; ++ks) {
            short8 af[4], bf[4];
            #pragma unroll
            for (int mt = 0; mt < 4; ++mt)
                af[mt] = *reinterpret_cast<const short8*>(
                    &lds_a[(wm + mt * 16 + r) * LDA + ks * 32 + q * 8]);
            #pragma unroll
            for (int nt = 0; nt < 4; ++nt)
                bf[nt] = *reinterpret_cast<const short8*>(
                    &lds_b[(wn + nt * 16 + r) * LDA + ks * 32 + q * 8]);
            #pragma unroll
            for (int mt = 0; mt < 4; ++mt)
                #pragma unroll
                for (int nt = 0; nt < 4; ++nt)
                    acc[mt][nt] = __builtin_amdgcn_mfma_f32_16x16x32_bf16(
                        af[mt], bf[nt], acc[mt][nt], 0, 0, 0);
        }
        __syncthreads();
    }

    // ---- epilogue: scale by s/norm^2 and store ----
    const float scale = 5.0f / norm2p[0];
    float* Cb = out_scores + (size_t)bp * (128 * 128);
    #pragma unroll
    for (int mt = 0; mt < 4; ++mt) {
        #pragma unroll
        for (int nt = 0; nt < 4; ++nt) {
            int col  = wn + nt * 16 + r;
            int row0 = wm + mt * 16 + q * 4;
            #pragma unroll
            for (int e = 0; e < 4; ++e)
                Cb[(size_t)(row0 + e) * 128 + col] = acc[mt][nt][e] * scale;
        }
    }

    // ---- fused first-match targets (argmax of equality mask) ----
    // tj_s was filled before the main loop; all __syncthreads since then keep it valid.
    if (tid < 128) {
        int t0 = target[(size_t)(b * 16 + i) * 128 + tid];
        int found = 0;
        for (int v = 127; v >= 0; --v)
            if (tj_s[v] == t0) found = v;   // smallest matching v; 0 if none
        out_tgt[(size_t)bp * 128 + tid] = (float)found;
    }
}

extern "C" void kernel_launch(void* const* d_in, const int* in_sizes, int n_in,
                              void* d_out, int out_size, void* d_ws, size_t ws_size,
                              hipStream_t stream) {
    const float* x      = (const float*)d_in[0];
    const int*   target = (const int*)d_in[1];
    float* out        = (float*)d_out;
    float* out_scores = out;                          // 32*120*128*128 floats
    float* out_tgt    = out + (size_t)32 * 120 * 128 * 128;
    float* norm2      = (float*)d_ws;

    hipMemsetAsync(d_ws, 0, sizeof(float), stream);
    sumsq_kernel<<<1024, BDIM, 0, stream>>>(x, norm2, in_sizes[0] / 4);
    pair_gemm_kernel<<<32 * 120, BDIM, 0, stream>>>(x, target, norm2,
                                                    out_scores, out_tgt);
}

// Round 2
// 369.206 us; speedup vs baseline: 1.1364x; 1.1364x over previous
//
#include <hip/hip_runtime.h>

// ---------------------------------------------------------------------------
// Arcface-like: xn = x/||x||_F ; scores[b,p,w,v] = 5 * dot(xn[b,i,w,:], xn[b,j,v,:])
//   for (i,j) = triu_indices(16, k=1)[p], plus first-match targets.
// B=32, S=16, W=128, h=256, P=120.
// Round 2: pre-convert x->bf16 once into d_ws (fused with norm reduction),
// global_load_lds(16B) staging with XOR source-swizzle (conflict-free
// ds_read_b128 without padding), swapped MFMA operands for float4 C-stores,
// 4 blocks/CU. Fallback to round-1 in-kernel-convert path if ws too small.
// ---------------------------------------------------------------------------

typedef __attribute__((ext_vector_type(8))) short short8;   // 8 bf16 in 4 VGPRs
typedef __attribute__((ext_vector_type(4))) float floatx4;  // MFMA accumulator

#define BDIM 256
#define XB_BYTES (32u * 1024u * 1024u)   // 16.7M bf16 elems

static __device__ __forceinline__ unsigned int f2bf(float f) {
    unsigned int u = __builtin_bit_cast(unsigned int, f);
    u += 0x7FFFu + ((u >> 16) & 1u);
    return u >> 16;
}

static __device__ __forceinline__ void gload_lds16(const unsigned short* g,
                                                   unsigned short* l) {
    __builtin_amdgcn_global_load_lds(
        (const __attribute__((address_space(1))) unsigned int*)g,
        (__attribute__((address_space(3))) unsigned int*)l, 16, 0, 0);
}

// -------- Kernel 1: fp32 -> bf16 convert + fused sum-of-squares -------------
__global__ void convert_sumsq_kernel(const float* __restrict__ x,
                                     unsigned short* __restrict__ xb,
                                     float* __restrict__ norm2, int n8) {
    const float4* x4 = reinterpret_cast<const float4*>(x);
    uint4* xb4 = reinterpret_cast<uint4*>(xb);
    int tid = blockIdx.x * blockDim.x + threadIdx.x;
    int stride = gridDim.x * blockDim.x;
    float s = 0.f;
    for (int c = tid; c < n8; c += stride) {
        float4 a = x4[2 * c], b = x4[2 * c + 1];
        s += a.x * a.x + a.y * a.y + a.z * a.z + a.w * a.w;
        s += b.x * b.x + b.y * b.y + b.z * b.z + b.w * b.w;
        uint4 pk;
        pk.x = f2bf(a.x) | (f2bf(a.y) << 16);
        pk.y = f2bf(a.z) | (f2bf(a.w) << 16);
        pk.z = f2bf(b.x) | (f2bf(b.y) << 16);
        pk.w = f2bf(b.z) | (f2bf(b.w) << 16);
        xb4[c] = pk;
    }
    #pragma unroll
    for (int off = 32; off > 0; off >>= 1) s += __shfl_down(s, off, 64);
    __shared__ float ws[4];
    int lane = threadIdx.x & 63, wv = threadIdx.x >> 6;
    if (lane == 0) ws[wv] = s;
    __syncthreads();
    if (threadIdx.x == 0) atomicAdd(norm2, ws[0] + ws[1] + ws[2] + ws[3]);
}

// -------- Kernel 2: per-(b,p) 128x128x256 NT-GEMM (bf16 in) + targets -------
__global__ __launch_bounds__(BDIM, 4) void pair_gemm_bf16_kernel(
    const unsigned short* __restrict__ xb, const int* __restrict__ target,
    const float* __restrict__ norm2p, float* __restrict__ out_scores,
    float* __restrict__ out_tgt)
{
    // Unpadded: row stride 64 bf16 = 128 B. Chunk (row, c8) lives at slot
    // row*8 + (c8 ^ (row&7))  (16B chunks) — XOR swizzle kills bank conflicts.
    __shared__ __align__(16) unsigned short lds_a[128 * 64];
    __shared__ __align__(16) unsigned short lds_b[128 * 64];
    __shared__ int tj_s[128];

    const int bp = blockIdx.x;        // 0..3839
    const int b  = bp / 120;
    const int p  = bp - b * 120;
    int i = 0, rem = p;
    while (rem >= 15 - i) { rem -= 15 - i; ++i; }
    const int j = i + 1 + rem;

    const unsigned short* Ag = xb + (size_t)(b * 16 + i) * (128 * 256);
    const unsigned short* Bg = xb + (size_t)(b * 16 + j) * (128 * 256);

    const int tid  = threadIdx.x;
    const int lane = tid & 63;
    const int wave = tid >> 6;
    const int wrow = (wave >> 1) * 64;   // w (A-row) offset of this wave's tile
    const int wcol = (wave & 1)  * 64;   // v (B-row) offset
    const int r    = lane & 15;
    const int q    = lane >> 4;

    if (tid < 128) tj_s[tid] = target[(size_t)(b * 16 + j) * 128 + tid];

    // staging addresses (invariant except k0)
    const int slot0 = wave * 64 + lane;          // base slot for it=0
    floatx4 acc[4][4] = {};

    for (int k0 = 0; k0 < 256; k0 += 64) {
        #pragma unroll
        for (int it = 0; it < 4; ++it) {
            int slot = it * 256 + slot0;         // 0..1023
            int row  = slot >> 3;
            int c8   = (slot & 7) ^ (row & 7);   // which global chunk fills this slot
            const unsigned short* ga = Ag + (size_t)row * 256 + k0 + c8 * 8;
            const unsigned short* gb = Bg + (size_t)row * 256 + k0 + c8 * 8;
            // wave-uniform LDS base; HW adds lane*16
            unsigned short* la = &lds_a[(size_t)(it * 256 + wave * 64) * 8];
            unsigned short* lb = &lds_b[(size_t)(it * 256 + wave * 64) * 8];
            gload_lds16(ga, la);
            gload_lds16(gb, lb);
        }
        __syncthreads();   // compiler emits vmcnt(0) drain before s_barrier

        #pragma unroll
        for (int ks = 0; ks < 2; ++ks) {
            const int swz = ((ks * 4 + q) ^ (r & 7)) * 8;   // lane-uniform across tiles
            short8 af[4], bf[4];
            #pragma unroll
            for (int wt = 0; wt < 4; ++wt)
                af[wt] = *reinterpret_cast<const short8*>(
                    &lds_a[(wrow + wt * 16 + r) * 64 + swz]);
            #pragma unroll
            for (int vt = 0; vt < 4; ++vt)
                bf[vt] = *reinterpret_cast<const short8*>(
                    &lds_b[(wcol + vt * 16 + r) * 64 + swz]);
            #pragma unroll
            for (int vt = 0; vt < 4; ++vt)
                #pragma unroll
                for (int wt = 0; wt < 4; ++wt)
                    // operand swap: D rows = v (from B), D cols = w (from A)
                    acc[vt][wt] = __builtin_amdgcn_mfma_f32_16x16x32_bf16(
                        bf[vt], af[wt], acc[vt][wt], 0, 0, 0);
        }
        __syncthreads();
    }

    // ---- epilogue: lane holds C[w = wrow+wt*16+r][v = wcol+vt*16+q*4+e] ----
    const float scale = 5.0f / norm2p[0];
    float* Cb = out_scores + (size_t)bp * (128 * 128);
    #pragma unroll
    for (int wt = 0; wt < 4; ++wt) {
        const int w = wrow + wt * 16 + r;
        #pragma unroll
        for (int vt = 0; vt < 4; ++vt) {
            float4 o;
            o.x = acc[vt][wt][0] * scale;
            o.y = acc[vt][wt][1] * scale;
            o.z = acc[vt][wt][2] * scale;
            o.w = acc[vt][wt][3] * scale;
            *reinterpret_cast<float4*>(&Cb[(size_t)w * 128 + wcol + vt * 16 + q * 4]) = o;
        }
    }

    if (tid < 128) {
        int t0 = target[(size_t)(b * 16 + i) * 128 + tid];
        int found = 0;
        for (int v = 127; v >= 0; --v)
            if (tj_s[v] == t0) found = v;
        out_tgt[(size_t)bp * 128 + tid] = (float)found;
    }
}

// ======================= Fallback path (round-1, fp32 in) ===================
#define LDA 72
__global__ void sumsq_kernel(const float* __restrict__ x,
                             float* __restrict__ out, int n4) {
    const float4* x4 = reinterpret_cast<const float4*>(x);
    int tid = blockIdx.x * blockDim.x + threadIdx.x;
    int stride = gridDim.x * blockDim.x;
    float s = 0.f;
    for (int idx = tid; idx < n4; idx += stride) {
        float4 v = x4[idx];
        s += v.x * v.x + v.y * v.y + v.z * v.z + v.w * v.w;
    }
    #pragma unroll
    for (int off = 32; off > 0; off >>= 1) s += __shfl_down(s, off, 64);
    __shared__ float ws[4];
    int lane = threadIdx.x & 63, wv = threadIdx.x >> 6;
    if (lane == 0) ws[wv] = s;
    __syncthreads();
    if (threadIdx.x == 0) atomicAdd(out, ws[0] + ws[1] + ws[2] + ws[3]);
}

__global__ __launch_bounds__(BDIM, 2) void pair_gemm_kernel(
    const float* __restrict__ x, const int* __restrict__ target,
    const float* __restrict__ norm2p, float* __restrict__ out_scores,
    float* __restrict__ out_tgt)
{
    __shared__ __align__(16) unsigned short lds_a[128 * LDA];
    __shared__ __align__(16) unsigned short lds_b[128 * LDA];
    __shared__ int tj_s[128];

    const int bp = blockIdx.x;
    const int b  = bp / 120;
    const int p  = bp - b * 120;
    int i = 0, rem = p;
    while (rem >= 15 - i) { rem -= 15 - i; ++i; }
    const int j = i + 1 + rem;

    const float* Ag = x + (size_t)(b * 16 + i) * (128 * 256);
    const float* Bg = x + (size_t)(b * 16 + j) * (128 * 256);

    const int tid  = threadIdx.x;
    const int lane = tid & 63;
    const int wave = tid >> 6;
    const int wm   = (wave >> 1) * 64;
    const int wn   = (wave & 1)  * 64;
    const int r    = lane & 15;
    const int q    = lane >> 4;

    if (tid < 128) tj_s[tid] = target[(size_t)(b * 16 + j) * 128 + tid];

    floatx4 acc[4][4] = {};

    for (int k0 = 0; k0 < 256; k0 += 64) {
        #pragma unroll
        for (int it = 0; it < 8; ++it) {
            int f   = it * BDIM + tid;
            int row = f >> 4;
            int c4  = (f & 15) * 4;
            float4 av = *reinterpret_cast<const float4*>(Ag + (size_t)row * 256 + k0 + c4);
            float4 bv = *reinterpret_cast<const float4*>(Bg + (size_t)row * 256 + k0 + c4);
            uint2 pa, pb;
            pa.x = f2bf(av.x) | (f2bf(av.y) << 16);
            pa.y = f2bf(av.z) | (f2bf(av.w) << 16);
            pb.x = f2bf(bv.x) | (f2bf(bv.y) << 16);
            pb.y = f2bf(bv.z) | (f2bf(bv.w) << 16);
            *reinterpret_cast<uint2*>(&lds_a[row * LDA + c4]) = pa;
            *reinterpret_cast<uint2*>(&lds_b[row * LDA + c4]) = pb;
        }
        __syncthreads();
        #pragma unroll
        for (int ks = 0; ks < 2; ++ks) {
            short8 af[4], bf[4];
            #pragma unroll
            for (int mt = 0; mt < 4; ++mt)
                af[mt] = *reinterpret_cast<const short8*>(
                    &lds_a[(wm + mt * 16 + r) * LDA + ks * 32 + q * 8]);
            #pragma unroll
            for (int nt = 0; nt < 4; ++nt)
                bf[nt] = *reinterpret_cast<const short8*>(
                    &lds_b[(wn + nt * 16 + r) * LDA + ks * 32 + q * 8]);
            #pragma unroll
            for (int mt = 0; mt < 4; ++mt)
                #pragma unroll
                for (int nt = 0; nt < 4; ++nt)
                    acc[mt][nt] = __builtin_amdgcn_mfma_f32_16x16x32_bf16(
                        af[mt], bf[nt], acc[mt][nt], 0, 0, 0);
        }
        __syncthreads();
    }

    const float scale = 5.0f / norm2p[0];
    float* Cb = out_scores + (size_t)bp * (128 * 128);
    #pragma unroll
    for (int mt = 0; mt < 4; ++mt) {
        #pragma unroll
        for (int nt = 0; nt < 4; ++nt) {
            int col  = wn + nt * 16 + r;
            int row0 = wm + mt * 16 + q * 4;
            #pragma unroll
            for (int e = 0; e < 4; ++e)
                Cb[(size_t)(row0 + e) * 128 + col] = acc[mt][nt][e] * scale;
        }
    }

    if (tid < 128) {
        int t0 = target[(size_t)(b * 16 + i) * 128 + tid];
        int found = 0;
        for (int v = 127; v >= 0; --v)
            if (tj_s[v] == t0) found = v;
        out_tgt[(size_t)bp * 128 + tid] = (float)found;
    }
}

// ============================================================================
extern "C" void kernel_launch(void* const* d_in, const int* in_sizes, int n_in,
                              void* d_out, int out_size, void* d_ws, size_t ws_size,
                              hipStream_t stream) {
    const float* x      = (const float*)d_in[0];
    const int*   target = (const int*)d_in[1];
    float* out        = (float*)d_out;
    float* out_scores = out;
    float* out_tgt    = out + (size_t)32 * 120 * 128 * 128;

    if (ws_size >= XB_BYTES + 64) {
        unsigned short* xb = (unsigned short*)d_ws;
        float* norm2 = (float*)((char*)d_ws + XB_BYTES);
        hipMemsetAsync(norm2, 0, sizeof(float), stream);
        convert_sumsq_kernel<<<2048, BDIM, 0, stream>>>(x, xb, norm2,
                                                        in_sizes[0] / 8);
        pair_gemm_bf16_kernel<<<32 * 120, BDIM, 0, stream>>>(
            xb, target, norm2, out_scores, out_tgt);
    } else {
        float* norm2 = (float*)d_ws;
        hipMemsetAsync(norm2, 0, sizeof(float), stream);
        sumsq_kernel<<<1024, BDIM, 0, stream>>>(x, norm2, in_sizes[0] / 4);
        pair_gemm_kernel<<<32 * 120, BDIM, 0, stream>>>(x, target, norm2,
                                                        out_scores, out_tgt);
    }
}